// Round 5
// baseline (236.809 us; speedup 1.0000x reference)
//
#include <hip/hip_runtime.h>
#include <cstdint>
#include <cstddef>

typedef unsigned int u32;
typedef unsigned long long u64;

#define NB 8192
#define BIMG 2
#define WPR (NB / 64)   // 128 u64 words per mask row

// ---------------- workspace layout (bytes) ----------------
#define WS_KCOUNT 0
#define WS_KEYS   256
#define WS_BOXES  (WS_KEYS + BIMG * NB * 8)          // 131328
#define WS_PROB   (WS_BOXES + BIMG * NB * 16)        // 393472
#define WS_SBOXES (WS_PROB + BIMG * NB * 4)          // 459008
#define WS_SPROB  (WS_SBOXES + BIMG * NB * 16)       // 721152
#define WS_REMV   (WS_SPROB + BIMG * NB * 4)         // 786688
#define WS_MASK   (WS_REMV + BIMG * WPR * 8 + 256)   // 788992 (pad)
#define WS_ROWNZ  (WS_MASK + (size_t)BIMG * NB * WPR * 8)
#define WS_NEEDED (WS_ROWNZ + (size_t)BIMG * NB)     // ~17.6 MB

// ---------------------------------------------------------------------------
// Kernel 1: sigmoid + box decode + sort-key build (NO atomics)
// ---------------------------------------------------------------------------
__global__ void decode_kernel(const float* __restrict__ offsets,
                              const float* __restrict__ labels,
                              const float* __restrict__ anchors,
                              u64* __restrict__ keys,
                              float4* __restrict__ boxes,
                              float* __restrict__ prob) {
  int idx = blockIdx.x * blockDim.x + threadIdx.x;
  if (idx >= BIMG * NB) return;
  int n = idx & (NB - 1);

  float logit = labels[idx];
  float p = 1.0f / (1.0f + expf(-logit));
  bool valid = p > 0.5f;

  const float4 an = ((const float4*)anchors)[n];   // x1,y1,x2,y2
  float acx = (an.x + an.z) / 2.0f;
  float acy = (an.y + an.w) / 2.0f;
  float aw = an.z - an.x;
  float ah = an.w - an.y;

  const float4 of = ((const float4*)offsets)[idx]; // gcx,gcy,gw,gh
  float cx = of.x * aw / 10.0f + acx;
  float cy = of.y * ah / 10.0f + acy;
  float w = expf(of.z / 5.0f) * aw;
  float h = expf(of.w / 5.0f) * ah;

  float4 bx;
  bx.x = cx - w / 2.0f;
  bx.y = cy - h / 2.0f;
  bx.z = cx + w / 2.0f;
  bx.w = cy + h / 2.0f;
  boxes[idx] = bx;
  prob[idx] = p;

  u32 e = valid ? (__float_as_uint(p) ^ 0x80000000u) : 0u;
  keys[idx] = ((u64)e << 32) | (u32)(~(u32)n);
}

// ---------------------------------------------------------------------------
// Kernel 2: per-image bitonic sort (desc) + valid count + fused sorted gather
// LDS index swizzle IX: bijective XOR of low-4 bits by f(high bits) —
// flattens the 4-8-way bank conflicts of the small-j bitonic phases.
// ---------------------------------------------------------------------------
#define IX(x) ((x) ^ ((((x) >> 4) * 5) & 15))

__global__ __launch_bounds__(1024) void sort_kernel(u64* __restrict__ keys,
                                                    const float4* __restrict__ boxes,
                                                    const float* __restrict__ prob,
                                                    float4* __restrict__ sboxes,
                                                    float* __restrict__ sprob,
                                                    u32* __restrict__ kcount) {
  __shared__ u64 s[NB];                 // 64 KB
  __shared__ u32 scnt;
  const int b = blockIdx.x;
  u64* kb = keys + (size_t)b * NB;
  if (threadIdx.x == 0) scnt = 0;
  u32 lc = 0;
  for (int i = threadIdx.x; i < NB; i += 1024) {
    u64 k = kb[i];
    s[IX(i)] = k;
    lc += ((u32)(k >> 32) != 0u) ? 1u : 0u;
  }
  // wave reduction of local valid count
  for (int off = 32; off > 0; off >>= 1) lc += __shfl_down(lc, off, 64);
  __syncthreads();                       // scnt init + s[] loaded
  if ((threadIdx.x & 63) == 0) atomicAdd(&scnt, lc);   // 16 LDS atomics
  __syncthreads();
  if (threadIdx.x == 0) kcount[b] = scnt;

  for (int k = 2; k <= NB; k <<= 1) {
    for (int j = k >> 1; j > 0; j >>= 1) {
      for (int p = threadIdx.x; p < NB / 2; p += 1024) {
        int i = ((p & ~(j - 1)) << 1) | (p & (j - 1));
        int ixj = i | j;
        u64 a = s[IX(i)];
        u64 c = s[IX(ixj)];
        bool desc = (i & k) == 0;
        if ((a < c) == desc) { s[IX(i)] = c; s[IX(ixj)] = a; }
      }
      __syncthreads();
    }
  }

  // write back keys + fused gather into sorted order
  const float4* bx = boxes + (size_t)b * NB;
  const float* pb = prob + (size_t)b * NB;
  for (int i = threadIdx.x; i < NB; i += 1024) {
    u64 k = s[IX(i)];
    kb[i] = k;
    u32 oi = (u32)(~k);                 // original anchor index
    sboxes[(size_t)b * NB + i] = bx[oi];
    sprob[(size_t)b * NB + i]  = pb[oi];
  }
}

// ---------------------------------------------------------------------------
// Kernel 4: overlap bitmask build + per-row nonzero flag.
// mask[b][i][w] bit l = (j=64w+l) > i && j < K && IoU(i,j) > 0.5
// ---------------------------------------------------------------------------
__global__ __launch_bounds__(256) void mask_kernel(const float4* __restrict__ sboxes,
                                                   const u32* __restrict__ kcount,
                                                   u64* __restrict__ mask,
                                                   unsigned char* __restrict__ rownz) {
  const int i = blockIdx.x;       // sorted row
  const int b = blockIdx.y;
  const int K = (int)kcount[b];
  if (i >= K) return;
  const int wave = threadIdx.x >> 6;
  const int lane = threadIdx.x & 63;
  __shared__ u32 anyf[4];
  const float4* sb = sboxes + (size_t)b * NB;
  const float4 bi = sb[i];
  const float area_i = (bi.z - bi.x) * (bi.w - bi.y);
  u64* mrow = mask + ((size_t)b * NB + i) * WPR;
  bool any = false;
  for (int pass = 0; pass < WPR / 4; ++pass) {
    int w = pass * 4 + wave;
    u64 word = 0;
    if ((w + 1) * 64 > i && w * 64 < K) {   // uniform per wave
      int j = w * 64 + lane;
      float4 bj = sb[j];
      float lx = fmaxf(bi.x, bj.x);
      float ly = fmaxf(bi.y, bj.y);
      float rx = fminf(bi.z, bj.z);
      float ry = fminf(bi.w, bj.w);
      float iw = fmaxf(rx - lx, 0.0f);
      float ih = fmaxf(ry - ly, 0.0f);
      float inter = iw * ih;
      float area_j = (bj.z - bj.x) * (bj.w - bj.y);
      float iou = inter / (area_i + area_j - inter);
      bool pred = (j > i) && (j < K) && (iou > 0.5f);
      word = __ballot(pred);
      any = any || (word != 0ull);
    }
    if (lane == 0) mrow[w] = word;
  }
  if (lane == 0) anyf[wave] = any ? 1u : 0u;
  __syncthreads();
  if (threadIdx.x == 0) {
    u32 a = anyf[0] | anyf[1] | anyf[2] | anyf[3];
    rownz[(size_t)b * NB + i] = (unsigned char)(a ? 1 : 0);
  }
}

// ---------------------------------------------------------------------------
// Kernel 5: chunked greedy scan, 1 wave per image.
// Per chunk: resolve 64x64 diagonal serially (readlane loop over nonzero
// rows), then OR all kept rows' masks with ONE memory round trip (<=64
// loads issued in 4 guarded groups before a single wait). Words <= c of a
// chunk-c row are provably zero / already folded into rc -> skip (FETCH/2).
// ---------------------------------------------------------------------------
__device__ inline u64 rdl64(u64 v, int lane) {
  u32 lo = (u32)__builtin_amdgcn_readlane((int)(u32)v, lane);
  u32 hi = (u32)__builtin_amdgcn_readlane((int)(u32)(v >> 32), lane);
  return ((u64)hi << 32) | lo;
}

__global__ __launch_bounds__(64) void scan_kernel(const u64* __restrict__ mask,
                                                  const unsigned char* __restrict__ rownz,
                                                  const u32* __restrict__ kcount,
                                                  u64* __restrict__ remv) {
  const int b = blockIdx.x;
  const int lid = threadIdx.x;
  const int K = (int)kcount[b];
  const u64* mb = mask + (size_t)b * NB * WPR;
  const unsigned char* nzb = rownz + (size_t)b * NB;

  // init remv: bits >= K are suppressed from the start
  u64 r0, r1;
  {
    int w0 = 2 * lid, w1 = 2 * lid + 1;
    int lo0 = w0 * 64, lo1 = w1 * 64;
    r0 = (lo0 + 64 <= K) ? 0ull : ((lo0 >= K) ? ~0ull : ((~0ull) << (K - lo0)));
    r1 = (lo1 + 64 <= K) ? 0ull : ((lo1 >= K) ? ~0ull : ((~0ull) << (K - lo1)));
  }

  const int NC = min(WPR, (K + 63) >> 6);

  // prefetch chunk 0: diagonal word + rownz byte
  u64 dw = 0;
  unsigned char nzbyte = 0;
  if (NC > 0) {
    dw = (lid < K) ? mb[(size_t)lid * WPR + 0] : 0ull;
    nzbyte = nzb[lid];
  }

  for (int c = 0; c < NC; ++c) {
    // prefetch next chunk's diagonal block + rownz byte (hidden behind resolve)
    u64 dw_next = 0;
    unsigned char nz_next = 0;
    if (c + 1 < NC) {
      int i = (c + 1) * 64 + lid;
      dw_next = (i < K) ? mb[(size_t)i * WPR + (c + 1)] : 0ull;
      nz_next = nzb[(c + 1) * 64 + lid];
    }
    u64 nzword = __ballot(nzbyte != 0);   // stale rows beyond K masked by rc

    const int owner = c >> 1;
    u64 rc = rdl64((c & 1) ? r1 : r0, owner);   // current suppressed word (uniform)

    // within-chunk resolution: ascending order over rows with nonzero diag word
    u64 nzd = __ballot(dw != 0ull);
    while (nzd) {
      int l = __builtin_ctzll(nzd);
      nzd &= nzd - 1;
      if (((rc >> l) & 1ull) == 0ull) {
        rc |= rdl64(dw, l);
      }
    }
    if (lid == owner) { if (c & 1) r1 = rc; else r0 = rc; }

    // OR full mask rows of kept boxes: <=64 rows, ALL loads issued before one
    // wait. Lane lid covers words 2lid,2lid+1; skip when both <= c (zero /
    // already in rc).
    u64 ku = (~rc) & nzword;
    if (ku) {
      int last = __builtin_ctzll(ku);
      u64 kk = ku;
      const bool wok = (2 * lid + 1) > c;
      ulonglong2 v[64];
#define LOADQ(q) { int l_ = kk ? __builtin_ctzll(kk) : last; if (kk) kk &= kk - 1; \
        ulonglong2 t_; \
        if (wok) t_ = ((const ulonglong2*)(mb + (size_t)(c * 64 + l_) * WPR))[lid]; \
        else { t_.x = 0; t_.y = 0; } \
        v[q] = t_; }
#pragma unroll
      for (int q = 0; q < 16; ++q) LOADQ(q)
      const bool g1 = kk != 0ull;
      if (g1) {
#pragma unroll
        for (int q = 16; q < 32; ++q) LOADQ(q)
      }
      const bool g2 = kk != 0ull;
      if (g2) {
#pragma unroll
        for (int q = 32; q < 48; ++q) LOADQ(q)
      }
      const bool g3 = kk != 0ull;
      if (g3) {
#pragma unroll
        for (int q = 48; q < 64; ++q) LOADQ(q)
      }
#undef LOADQ
#pragma unroll
      for (int q = 0; q < 16; ++q) { r0 |= v[q].x; r1 |= v[q].y; }
      if (g1) {
#pragma unroll
        for (int q = 16; q < 32; ++q) { r0 |= v[q].x; r1 |= v[q].y; }
      }
      if (g2) {
#pragma unroll
        for (int q = 32; q < 48; ++q) { r0 |= v[q].x; r1 |= v[q].y; }
      }
      if (g3) {
#pragma unroll
        for (int q = 48; q < 64; ++q) { r0 |= v[q].x; r1 |= v[q].y; }
      }
    }
    dw = dw_next;
    nzbyte = nz_next;
  }
  remv[(size_t)b * WPR + 2 * lid]     = r0;
  remv[(size_t)b * WPR + 2 * lid + 1] = r1;
}

// ---------------------------------------------------------------------------
// Kernel 6: output write
// ---------------------------------------------------------------------------
__global__ void output_kernel(const float4* __restrict__ sboxes,
                              const float* __restrict__ sprob,
                              const u64* __restrict__ remv,
                              const u32* __restrict__ kcount,
                              float* __restrict__ out) {
  int idx = blockIdx.x * blockDim.x + threadIdx.x;
  if (idx >= BIMG * NB) return;
  int b = idx / NB;
  int p = idx - b * NB;
  int K = (int)kcount[b];
  u64 w = remv[(size_t)b * WPR + (p >> 6)];
  bool kp = (p < K) && !((w >> (p & 63)) & 1ull);
  float4 bv = sboxes[idx];
  if (!kp) { bv.x = 0.0f; bv.y = 0.0f; bv.z = 0.0f; bv.w = 0.0f; }
  ((float4*)out)[idx] = bv;
  out[(size_t)BIMG * NB * 4 + idx] = kp ? sprob[idx] : 0.0f;
  out[(size_t)BIMG * NB * 5 + idx] = kp ? 1.0f : 0.0f;
}

// ---------------------------------------------------------------------------
// Fallback NMS kernel (used only if workspace is too small)
// ---------------------------------------------------------------------------
__global__ __launch_bounds__(1024) void nms_kernel(const u64* __restrict__ keys,
                                                   const float4* __restrict__ boxes,
                                                   const float* __restrict__ prob,
                                                   const u32* __restrict__ kcount,
                                                   float* __restrict__ out) {
  __shared__ float4 sb[NB];
  __shared__ unsigned char flag[NB];
  const int b = blockIdx.x;
  const int t = threadIdx.x;
  const u64* kb = keys + (size_t)b * NB;
  const float4* bx = boxes + (size_t)b * NB;
  const int K = (int)kcount[b];

  for (int p = t; p < NB; p += 1024) {
    u32 idx = (u32)(~kb[p]);
    sb[p] = bx[idx];
    flag[p] = (p < K) ? (unsigned char)0 : (unsigned char)1;
  }
  __syncthreads();

  for (int i = 0; i < K; ++i) {
    if (flag[i]) continue;
    float4 bi = sb[i];
    float area_i = (bi.z - bi.x) * (bi.w - bi.y);
    for (int j = i + 1 + t; j < K; j += 1024) {
      float4 bj = sb[j];
      float lx = fmaxf(bi.x, bj.x);
      float ly = fmaxf(bi.y, bj.y);
      float rx = fminf(bi.z, bj.z);
      float ry = fminf(bi.w, bj.w);
      float iw = fmaxf(rx - lx, 0.0f);
      float ih = fmaxf(ry - ly, 0.0f);
      float inter = iw * ih;
      float area_j = (bj.z - bj.x) * (bj.w - bj.y);
      float iou = inter / (area_i + area_j - inter);
      if (iou > 0.5f) flag[j] = (unsigned char)1;
    }
    __syncthreads();
  }

  float4* oboxes = (float4*)(out) + (size_t)b * NB;
  float* oscores = out + (size_t)BIMG * NB * 4 + (size_t)b * NB;
  float* okeep   = out + (size_t)BIMG * NB * 5 + (size_t)b * NB;
  const float* pb = prob + (size_t)b * NB;
  for (int p = t; p < NB; p += 1024) {
    bool kp = (p < K) && (flag[p] == 0);
    float4 bv = sb[p];
    if (!kp) { bv.x = 0.0f; bv.y = 0.0f; bv.z = 0.0f; bv.w = 0.0f; }
    oboxes[p] = bv;
    u32 idx = (u32)(~kb[p]);
    oscores[p] = kp ? pb[idx] : 0.0f;
    okeep[p] = kp ? 1.0f : 0.0f;
  }
}

// ---------------------------------------------------------------------------
extern "C" void kernel_launch(void* const* d_in, const int* in_sizes, int n_in,
                              void* d_out, int out_size, void* d_ws, size_t ws_size,
                              hipStream_t stream) {
  const float* offsets = (const float*)d_in[0];   // [B,N,4] f32
  const float* labels  = (const float*)d_in[1];   // [B,N,1] f32
  const float* anchors = (const float*)d_in[2];   // [N,4]   f32
  float* out = (float*)d_out;

  char* ws = (char*)d_ws;
  u32*    kcount = (u32*)(ws + WS_KCOUNT);
  u64*    keys   = (u64*)(ws + WS_KEYS);
  float4* boxes  = (float4*)(ws + WS_BOXES);
  float*  prob   = (float*)(ws + WS_PROB);
  float4* sboxes = (float4*)(ws + WS_SBOXES);
  float*  sprob  = (float*)(ws + WS_SPROB);

  int total = BIMG * NB;
  decode_kernel<<<(total + 255) / 256, 256, 0, stream>>>(
      offsets, labels, anchors, keys, boxes, prob);

  sort_kernel<<<BIMG, 1024, 0, stream>>>(keys, boxes, prob, sboxes, sprob, kcount);

  if (ws_size >= WS_NEEDED) {
    u64*    remv   = (u64*)(ws + WS_REMV);
    u64*    mask   = (u64*)(ws + WS_MASK);
    unsigned char* rownz = (unsigned char*)(ws + WS_ROWNZ);

    mask_kernel<<<dim3(NB, BIMG), 256, 0, stream>>>(sboxes, kcount, mask, rownz);

    scan_kernel<<<BIMG, 64, 0, stream>>>(mask, rownz, kcount, remv);

    output_kernel<<<(total + 255) / 256, 256, 0, stream>>>(
        sboxes, sprob, remv, kcount, out);
  } else {
    nms_kernel<<<BIMG, 1024, 0, stream>>>(keys, boxes, prob, kcount, out);
  }
}